// Round 1
// 646.339 us; speedup vs baseline: 2.0956x; 2.0956x over previous
//
#include <hip/hip_runtime.h>

// Problem: B=64, C=256, H=W=56, HEADS=16, DH=16, WS=7, n1=n2=8, eps=1e-6
// Round-1 restructure: the old fused k2 (proj+attn per head) was latency-bound
// (24% occupancy from 64KB LDS, 16 barrier-drained staging rounds/block, A panel
// re-staged 16x across heads, MfmaUtil 4.8%). Split into:
//   k0: pack qk_w/v_w f32 -> bf16 once, head-major rows (n = head*48 + {q16,k16,v16})
//   k1: unchanged BN+window-gather -> A_ws[token][256] bf16 (token = window*49+tok)
//   k2a: GEMM per (window, 4 heads): M=64(pad of 49) x N=192 x K=256 -> per-(win,head)
//        tiles Q[49][16], K[49][16], VT[16][52] bf16 (VT transposed+ReLU in epilogue)
//   k2b: attention per (b,win_h,head), wave = 2 windows, frags loaded straight from
//        global (each frag load = contiguous 512B/wave), LDS only for O assembly.
// Workspace: A_ws 98MB + Wb 0.4MB + QKV 4.92MB/batch-image; chunks batch if tight.

typedef unsigned short u16;
typedef __attribute__((ext_vector_type(4))) float f32x4;
typedef __attribute__((ext_vector_type(8))) short short8;
typedef __attribute__((ext_vector_type(4))) short short4b;

__device__ __forceinline__ u16 f2bf(float f) {
  union { float f; unsigned int i; } v; v.f = f;
  unsigned int r = v.i + 0x7fffu + ((v.i >> 16) & 1u);   // RNE
  return (u16)(r >> 16);
}

// K0: pack weights to bf16 once. 768 rows x 256 cols; row n = head*48+sub,
// sub 0..15 = q, 16..31 = k, 32..47 = v. 24576 octet-tasks = 96 blocks x 256.
__global__ __launch_bounds__(256) void k0_wpack(
    const float* __restrict__ qkw, const float* __restrict__ vw,
    u16* __restrict__ wb)
{
  int idx = blockIdx.x * 256 + threadIdx.x;
  int n = idx >> 5, oct = idx & 31;
  int head = n / 48, sub = n - head * 48;
  const float* src;
  if (sub < 16)      src = qkw + (size_t)(head * 16 + sub) * 256;
  else if (sub < 32) src = qkw + (size_t)(256 + head * 16 + (sub - 16)) * 256;
  else               src = vw  + (size_t)(head * 16 + (sub - 32)) * 256;
  src += oct * 8;
  float4 a = *(const float4*)src;
  float4 c = *(const float4*)(src + 4);
  uint4 pk;
  pk.x = (unsigned)f2bf(a.x) | ((unsigned)f2bf(a.y) << 16);
  pk.y = (unsigned)f2bf(a.z) | ((unsigned)f2bf(a.w) << 16);
  pk.z = (unsigned)f2bf(c.x) | ((unsigned)f2bf(c.y) << 16);
  pk.w = (unsigned)f2bf(c.z) | ((unsigned)f2bf(c.w) << 16);
  *(uint4*)(wb + (size_t)n * 256 + oct * 8) = pk;
}

// K1: eval-BN (f32) + transpose + window-gather -> A_ws[t'][c] bf16. (unchanged)
__global__ __launch_bounds__(256) void k1_bn_gather(
    const float* __restrict__ x, const float* __restrict__ g,
    const float* __restrict__ be, const float* __restrict__ mu,
    const float* __restrict__ va, u16* __restrict__ aws)
{
  __shared__ u16 lds[56 * 264];   // [w][c], c padded 256->264
  const int tid = threadIdx.x;
  const int bx = blockIdx.x;
  const int ws_h = bx % 7, win_h = (bx / 7) % 8, b = bx / 56;
  const int h = ws_h * 8 + win_h;

  for (int it = 0; it < 7; ++it) {
    int idx = it * 256 + tid;
    int c = idx / 7, oct = idx % 7;
    const float* src = x + (size_t)(b * 256 + c) * 3136 + h * 56 + oct * 8;
    float4 p0 = *(const float4*)src;
    float4 p1 = *(const float4*)(src + 4);
    float inv = g[c] * rsqrtf(va[c] + 1e-6f);
    float sh = be[c] - mu[c] * inv;
    float vals[8] = { p0.x, p0.y, p0.z, p0.w, p1.x, p1.y, p1.z, p1.w };
#pragma unroll
    for (int j = 0; j < 8; ++j)
      lds[(oct * 8 + j) * 264 + c] = f2bf(fmaf(vals[j], inv, sh));
  }
  __syncthreads();

  const size_t t0 = (size_t)(b * 64 + win_h * 8) * 49;
  for (int it = 0; it < 7; ++it) {
    int idx = it * 256 + tid;
    int tl = idx >> 5, coct = idx & 31;
    int win_w = tl / 7, ws_w = tl - win_w * 7;
    int w = ws_w * 8 + win_w;
    uint4 v = *(const uint4*)&lds[w * 264 + coct * 8];
    size_t tp = t0 + (size_t)win_w * 49 + ws_h * 7 + ws_w;
    *(uint4*)(aws + tp * 256 + coct * 8) = v;
  }
}

// K2a: QKV projection GEMM. Block = (window, N-block of 192 cols = 4 heads).
// M = 64 rows (window padded from 49; pad rows clamp-load row 48, stores predicated).
// 4 waves: wave wv owns cols wv*48..+47 = exactly head (wnb*4+wv)'s {q,k,v}.
// K-loop: 4 steps of BK=64, reg-staged LDS (pitch 72 u16: 2-way-free bank pattern).
// Epilogue writes per-(window,head) tile: Q[49][16] @0, K[49][16] @784,
// VT[16][52] @1568 (u16 offsets; ReLU'd V stored transposed: one 8B store/lane/frag).
__global__ __launch_bounds__(256, 4) void k2a_qkv(
    const u16* __restrict__ aws, const u16* __restrict__ wb,
    u16* __restrict__ qkv, int win0)
{
  __shared__ u16 sA[64 * 72];    //  9216 B
  __shared__ u16 sB[192 * 72];   // 27648 B  -> 36864 B total, 4 blocks/CU
  const int tid = threadIdx.x;
  const int lane = tid & 63, wv = tid >> 6;
  const int l15 = lane & 15, quad = lane >> 4;
  const int wnb = blockIdx.x & 3;
  const int tloc = blockIdx.x >> 2;               // chunk-local window
  const size_t arow0 = (size_t)(win0 + tloc) * 49 * 256;
  const int nb0 = wnb * 192;

  f32x4 acc[4][3];
#pragma unroll
  for (int i = 0; i < 4; ++i)
#pragma unroll
    for (int j = 0; j < 3; ++j) acc[i][j] = (f32x4)(0.0f);

  for (int kb = 0; kb < 4; ++kb) {
    __syncthreads();
    // stage A: 64 rows x 8 octets (rows >= 49 clamp to 48; garbage discarded at store)
#pragma unroll
    for (int it = 0; it < 2; ++it) {
      int idx = it * 256 + tid;
      int r = idx >> 3, oct = idx & 7;
      int rs = r < 49 ? r : 48;
      uint4 v = *(const uint4*)(aws + arow0 + (size_t)rs * 256 + kb * 64 + oct * 8);
      *(uint4*)&sA[r * 72 + oct * 8] = v;
    }
    // stage B: 192 rows x 8 octets (bf16 weights, L2-resident)
#pragma unroll
    for (int it = 0; it < 6; ++it) {
      int idx = it * 256 + tid;
      int r = idx >> 3, oct = idx & 7;
      uint4 v = *(const uint4*)(wb + (size_t)(nb0 + r) * 256 + kb * 64 + oct * 8);
      *(uint4*)&sB[r * 72 + oct * 8] = v;
    }
    __syncthreads();
#pragma unroll
    for (int ks = 0; ks < 2; ++ks) {             // two K=32 steps
      int col = ks * 32 + quad * 8;
      short8 bf[3];
#pragma unroll
      for (int nt = 0; nt < 3; ++nt)
        bf[nt] = *(const short8*)&sB[(wv * 48 + nt * 16 + l15) * 72 + col];
#pragma unroll
      for (int mt = 0; mt < 4; ++mt) {
        short8 af = *(const short8*)&sA[(mt * 16 + l15) * 72 + col];
#pragma unroll
        for (int nt = 0; nt < 3; ++nt)
          acc[mt][nt] = __builtin_amdgcn_mfma_f32_16x16x32_bf16(
              af, bf[nt], acc[mt][nt], 0, 0, 0);
      }
    }
  }

  // epilogue: acc row = token (mt*16+quad*4+r), col = l15 = channel within sub-block
  const int head = wnb * 4 + wv;
  u16* tile = qkv + (size_t)(tloc * 16 + head) * 2400;
  u16* Qt = tile;
  u16* Kt = tile + 784;
  u16* Vt = tile + 1568;
#pragma unroll
  for (int mt = 0; mt < 4; ++mt) {
#pragma unroll
    for (int r = 0; r < 4; ++r) {
      int tok = mt * 16 + quad * 4 + r;
      if (tok < 49) {
        Qt[tok * 16 + l15] = f2bf(acc[mt][0][r]);
        Kt[tok * 16 + l15] = f2bf(acc[mt][1][r]);
      }
    }
    // VT[d=l15][tok]: 4 consecutive toks per lane -> one 8B store (runs 4-aligned)
    int tok0 = mt * 16 + quad * 4;
    if (tok0 + 3 < 49) {
      short4b pv;
#pragma unroll
      for (int r = 0; r < 4; ++r) pv[r] = (short)f2bf(fmaxf(acc[mt][2][r], 0.0f));
      *(short4b*)&Vt[l15 * 52 + tok0] = pv;
    } else if (tok0 == 48) {
      Vt[l15 * 52 + 48] = f2bf(fmaxf(acc[mt][2][0], 0.0f));
      // cols 49..51 never written and never read (k2b kt=3 reads col 48 scalar)
    }
  }
}

// K2b: windowed attention + output assembly. Block = (b, win_h, head), 4 waves,
// wave = 2 windows. Q/K/VT frags load straight from the tiled qkv buffer
// (each frag load instr = 512B contiguous per wave). LDS only holds O (26.6KB).
__global__ __launch_bounds__(256, 5) void k2b_attn(
    const u16* __restrict__ qkv, float* __restrict__ out, int b0)
{
  __shared__ float sO[8][16 * 52];   // per-window O^T [d][q], pitch 52
  const int tid = threadIdx.x;
  const int lane = tid & 63, wv = tid >> 6;
  const int l15 = lane & 15, quad = lane >> 4, kbase = quad * 4;
  const int bx = blockIdx.x;
  const int head = bx & 15;
  const int win_h = (bx >> 4) & 7;
  const int bl = bx >> 7;                         // chunk-local image
  const float SM = 0.36067376022224085f;          // dh^-0.5 * log2(e)

  for (int rep = 0; rep < 2; ++rep) {
    int ww = wv * 2 + rep;
    const u16* tile = qkv +
        (size_t)(((bl * 64 + win_h * 8 + ww) * 16) + head) * 2400;
    const u16* Qt = tile;
    const u16* Kt = tile + 784;
    const u16* Vt = tile + 1568;

    short4b ka[4], qb[4];
#pragma unroll
    for (int t = 0; t < 4; ++t) {
      int rk = t * 16 + l15; rk = (rk > 48) ? 48 : rk;   // clamp: finite data
      ka[t] = *(const short4b*)&Kt[rk * 16 + kbase];
      qb[t] = *(const short4b*)&Qt[rk * 16 + kbase];
    }
    f32x4 zz = (f32x4)(0.0f);
    f32x4 s[4][4];                      // S^T tiles: [mt over ktok][nt over q]
#pragma unroll
    for (int mt = 0; mt < 4; ++mt)
#pragma unroll
      for (int nt = 0; nt < 4; ++nt)
        s[mt][nt] = __builtin_amdgcn_mfma_f32_16x16x16bf16_1k(
            ka[mt], qb[nt], zz, 0, 0, 0);

    float inv_sum[4];
    short4b pf[4][4];                   // P^T frags == B-operand layout
#pragma unroll
    for (int nt = 0; nt < 4; ++nt) {
      float m = -1e30f;
#pragma unroll
      for (int mt = 0; mt < 4; ++mt)
#pragma unroll
        for (int r = 0; r < 4; ++r) {
          int kt = mt * 16 + kbase + r;
          float v = (kt < 49) ? s[mt][nt][r] : -1e30f;
          m = fmaxf(m, v);
        }
      m = fmaxf(m, __shfl_xor(m, 16, 64));
      m = fmaxf(m, __shfl_xor(m, 32, 64));
      float sum = 0.0f;
#pragma unroll
      for (int mt = 0; mt < 4; ++mt)
#pragma unroll
        for (int r = 0; r < 4; ++r) {
          int kt = mt * 16 + kbase + r;
          float p = (kt < 49) ? exp2f((s[mt][nt][r] - m) * SM) : 0.0f;
          sum += p;
          pf[mt][nt][r] = (short)f2bf(p);
        }
      sum += __shfl_xor(sum, 16, 64);
      sum += __shfl_xor(sum, 32, 64);
      inv_sum[nt] = 1.0f / sum;        // defer normalize to epilogue
    }

    f32x4 o[4];
#pragma unroll
    for (int nt = 0; nt < 4; ++nt) o[nt] = zz;
#pragma unroll
    for (int kt = 0; kt < 4; ++kt) {
      short4b vfrag = (short4b)0;
      if (kt < 3)
        vfrag = *(const short4b*)&Vt[l15 * 52 + kt * 16 + kbase];
      else if (quad == 0)
        vfrag[0] = (short)Vt[l15 * 52 + 48];     // only ktok=48 real; pf=0 masks rest
#pragma unroll
      for (int nt = 0; nt < 4; ++nt)
        o[nt] = __builtin_amdgcn_mfma_f32_16x16x16bf16_1k(
            vfrag, pf[kt][nt], o[nt], 0, 0, 0);
    }

    // O^T: lane holds q = nt*16+l15 (col), d = kbase+r (row)
    float* sOw = sO[ww];
#pragma unroll
    for (int nt = 0; nt < 4; ++nt) {
      int q = nt * 16 + l15;
      if (q < 49) {
#pragma unroll
        for (int r = 0; r < 4; ++r)
          sOw[(kbase + r) * 52 + q] = o[nt][r] * inv_sum[nt];
      }
    }
  }
  __syncthreads();

  // coalesced f32 store: rows out[b][head*16+d][wsh*8+win_h][0..55]
  {
    int b = b0 + bl;
    size_t obase = (size_t)(b * 256 + head * 16) * 3136;
    for (int i = tid; i < 3136; i += 256) {     // float2 tasks
      int d = i / 196, rem = i - d * 196;
      int wsh = rem / 28, dwp = rem - wsh * 28;
      int w0 = dwp * 2, w1 = w0 + 1;
      const float* sO0 = sO[w0 & 7];
      const float* sO1 = sO[w1 & 7];
      float2 val;
      val.x = sO0[d * 52 + wsh * 7 + (w0 >> 3)];
      val.y = sO1[d * 52 + wsh * 7 + (w1 >> 3)];
      *(float2*)(out + obase + (size_t)d * 3136 +
                 (wsh * 8 + win_h) * 56 + w0) = val;
    }
  }
}

extern "C" void kernel_launch(void* const* d_in, const int* in_sizes, int n_in,
                              void* d_out, int out_size, void* d_ws, size_t ws_size,
                              hipStream_t stream) {
  const float* x   = (const float*)d_in[0];
  const float* g   = (const float*)d_in[1];
  const float* be  = (const float*)d_in[2];
  const float* mu  = (const float*)d_in[3];
  const float* va  = (const float*)d_in[4];
  const float* qkw = (const float*)d_in[5];
  const float* vw  = (const float*)d_in[6];
  float* outp = (float*)d_out;

  const size_t AWS_BYTES = (size_t)200704 * 256 * 2;   // 98.0 MB token matrix
  const size_t WB_BYTES  = (size_t)768 * 256 * 2;      // packed bf16 weights
  const size_t PER_B_QKV = (size_t)64 * 16 * 4800;     // 4.92 MB per image

  u16* aws = (u16*)d_ws;
  u16* wb  = (u16*)((char*)d_ws + AWS_BYTES);
  u16* qkv = (u16*)((char*)d_ws + AWS_BYTES + WB_BYTES);

  size_t fixed = AWS_BYTES + WB_BYTES;
  size_t avail = ws_size > fixed ? ws_size - fixed : 0;
  int bchunk = (int)(avail / PER_B_QKV);
  if (bchunk > 64) bchunk = 64;
  if (bchunk < 1)  bchunk = 1;   // requires ws_size >= ~108 MB

  k0_wpack<<<96, 256, 0, stream>>>(qkw, vw, wb);
  k1_bn_gather<<<64 * 8 * 7, 256, 0, stream>>>(x, g, be, mu, va, aws);
  for (int c = 0; c < 64; c += bchunk) {
    int nb = (64 - c < bchunk) ? (64 - c) : bchunk;
    k2a_qkv<<<nb * 64 * 4, 256, 0, stream>>>(aws, wb, qkv, c * 64);
    k2b_attn<<<nb * 128, 256, 0, stream>>>(qkv, outp, c);
  }
}

// Round 2
// 564.214 us; speedup vs baseline: 2.4006x; 1.1456x over previous
//
#include <hip/hip_runtime.h>

// Problem: B=64, C=256, H=W=56, HEADS=16, DH=16, WS=7, n1=n2=8, eps=1e-6
// Round-2: fuse projection + attention. Round-1's k2a/k2b split paid a 621 MB
// QKV round trip (write 307 + read 314 = ~100us at achievable BW) purely to
// move per-(window,head) tiles between kernels -- but after the GEMM each wave
// already holds one head's full Q,K,V in accumulators. Now: GEMM (unchanged
// structure) -> epilogue bounces Q/K/VT through the just-freed LDS (wave-
// private, NO barrier) -> per-wave attention -> direct f32 stores.
// Output stores are 4B-scattered (single window per block); an XCD-chunked
// block swizzle puts the 8 ww-sibling blocks of every output row (and the 4
// nb-siblings sharing an A panel) on the same XCD so L2 merges lines.
//   k0: pack qk_w/v_w f32 -> bf16 once, head-major rows
//   k1: BN + window-gather -> A_ws[token][256] bf16 (unchanged, next target)
//   k2: fused GEMM+attention, block = (window, head-quad), 4 waves = 4 heads
// Workspace: A_ws 98MB + Wb 0.4MB only (QKV buffer eliminated).

typedef unsigned short u16;
typedef __attribute__((ext_vector_type(4))) float f32x4;
typedef __attribute__((ext_vector_type(8))) short short8;
typedef __attribute__((ext_vector_type(4))) short short4b;

__device__ __forceinline__ u16 f2bf(float f) {
  union { float f; unsigned int i; } v; v.f = f;
  unsigned int r = v.i + 0x7fffu + ((v.i >> 16) & 1u);   // RNE
  return (u16)(r >> 16);
}

// K0: pack weights to bf16 once. 768 rows x 256 cols; row n = head*48+sub,
// sub 0..15 = q, 16..31 = k, 32..47 = v. 24576 octet-tasks = 96 blocks x 256.
__global__ __launch_bounds__(256) void k0_wpack(
    const float* __restrict__ qkw, const float* __restrict__ vw,
    u16* __restrict__ wb)
{
  int idx = blockIdx.x * 256 + threadIdx.x;
  int n = idx >> 5, oct = idx & 31;
  int head = n / 48, sub = n - head * 48;
  const float* src;
  if (sub < 16)      src = qkw + (size_t)(head * 16 + sub) * 256;
  else if (sub < 32) src = qkw + (size_t)(256 + head * 16 + (sub - 16)) * 256;
  else               src = vw  + (size_t)(head * 16 + (sub - 32)) * 256;
  src += oct * 8;
  float4 a = *(const float4*)src;
  float4 c = *(const float4*)(src + 4);
  uint4 pk;
  pk.x = (unsigned)f2bf(a.x) | ((unsigned)f2bf(a.y) << 16);
  pk.y = (unsigned)f2bf(a.z) | ((unsigned)f2bf(a.w) << 16);
  pk.z = (unsigned)f2bf(c.x) | ((unsigned)f2bf(c.y) << 16);
  pk.w = (unsigned)f2bf(c.z) | ((unsigned)f2bf(c.w) << 16);
  *(uint4*)(wb + (size_t)n * 256 + oct * 8) = pk;
}

// K1: eval-BN (f32) + transpose + window-gather -> A_ws[t'][c] bf16. (unchanged)
__global__ __launch_bounds__(256) void k1_bn_gather(
    const float* __restrict__ x, const float* __restrict__ g,
    const float* __restrict__ be, const float* __restrict__ mu,
    const float* __restrict__ va, u16* __restrict__ aws)
{
  __shared__ u16 lds[56 * 264];   // [w][c], c padded 256->264
  const int tid = threadIdx.x;
  const int bx = blockIdx.x;
  const int ws_h = bx % 7, win_h = (bx / 7) % 8, b = bx / 56;
  const int h = ws_h * 8 + win_h;

  for (int it = 0; it < 7; ++it) {
    int idx = it * 256 + tid;
    int c = idx / 7, oct = idx % 7;
    const float* src = x + (size_t)(b * 256 + c) * 3136 + h * 56 + oct * 8;
    float4 p0 = *(const float4*)src;
    float4 p1 = *(const float4*)(src + 4);
    float inv = g[c] * rsqrtf(va[c] + 1e-6f);
    float sh = be[c] - mu[c] * inv;
    float vals[8] = { p0.x, p0.y, p0.z, p0.w, p1.x, p1.y, p1.z, p1.w };
#pragma unroll
    for (int j = 0; j < 8; ++j)
      lds[(oct * 8 + j) * 264 + c] = f2bf(fmaf(vals[j], inv, sh));
  }
  __syncthreads();

  const size_t t0 = (size_t)(b * 64 + win_h * 8) * 49;
  for (int it = 0; it < 7; ++it) {
    int idx = it * 256 + tid;
    int tl = idx >> 5, coct = idx & 31;
    int win_w = tl / 7, ws_w = tl - win_w * 7;
    int w = ws_w * 8 + win_w;
    uint4 v = *(const uint4*)&lds[w * 264 + coct * 8];
    size_t tp = t0 + (size_t)win_w * 49 + ws_h * 7 + ws_w;
    *(uint4*)(aws + tp * 256 + coct * 8) = v;
  }
}

// K2: fused QKV GEMM + attention. Block = (window, 4-head group), 4 waves.
// GEMM: M=64 (window pad of 49), N=192 (4 heads x {q,k,v}), K=256, BK=64;
// wave wv owns head (nb*4+wv)'s 48 cols -> acc[4 mt][3 nt].
// Then: acc -> LDS tiles Q[64][20] K[64][20] VT[16][52] (wave-private region,
// overlaying dead sA/sB; no barrier), per-wave attention (q-split halves to
// bound VGPR), direct f32 scattered stores (XCD swizzle makes them L2-merge).
__global__ __launch_bounds__(256, 4) void k2_fused(
    const u16* __restrict__ aws, const u16* __restrict__ wb,
    float* __restrict__ out)
{
  __shared__ u16 smem[18432];          // 36864 B -> 4 blocks/CU
  u16* sA = smem;                      // [64][72]
  u16* sB = smem + 4608;               // [192][72]
  const int tid = threadIdx.x;
  const int lane = tid & 63, wv = tid >> 6;
  const int l15 = lane & 15, quad = lane >> 4, kbase = quad * 4;

  // XCD-chunked swizzle: logical L consecutive => same XCD (assuming bid%8=xcd).
  // L layout (inner->outer): ww(8), nb(4), wh(8), b(64). Siblings sharing an
  // output row (ww 0..7) and an A panel (nb 0..3) are L-adjacent => co-XCD.
  const int bid = blockIdx.x;
  const int L = (bid & 7) * 2048 + (bid >> 3);
  const int ww = L & 7, nb = (L >> 3) & 3, whg = L >> 5;  // whg = b*8+wh
  const int wh = whg & 7, b = whg >> 3;
  const int tloc = (whg << 3) | ww;                        // b*64+wh*8+ww
  const size_t arow0 = (size_t)tloc * 49 * 256;
  const int nb0 = nb * 192;

  f32x4 acc[4][3];
#pragma unroll
  for (int i = 0; i < 4; ++i)
#pragma unroll
    for (int j = 0; j < 3; ++j) acc[i][j] = (f32x4)(0.0f);

  for (int kb = 0; kb < 4; ++kb) {
    __syncthreads();
    // stage A: 64 rows x 8 octets (rows >= 49 clamp to 48; results discarded)
#pragma unroll
    for (int it = 0; it < 2; ++it) {
      int idx = it * 256 + tid;
      int r = idx >> 3, oct = idx & 7;
      int rs = r < 49 ? r : 48;
      uint4 v = *(const uint4*)(aws + arow0 + (size_t)rs * 256 + kb * 64 + oct * 8);
      *(uint4*)&sA[r * 72 + oct * 8] = v;
    }
    // stage B: 192 rows x 8 octets (bf16 weights, L2-resident)
#pragma unroll
    for (int it = 0; it < 6; ++it) {
      int idx = it * 256 + tid;
      int r = idx >> 3, oct = idx & 7;
      uint4 v = *(const uint4*)(wb + (size_t)(nb0 + r) * 256 + kb * 64 + oct * 8);
      *(uint4*)&sB[r * 72 + oct * 8] = v;
    }
    __syncthreads();
#pragma unroll
    for (int ks = 0; ks < 2; ++ks) {             // two K=32 steps
      int col = ks * 32 + quad * 8;
      short8 bf[3];
#pragma unroll
      for (int nt = 0; nt < 3; ++nt)
        bf[nt] = *(const short8*)&sB[(wv * 48 + nt * 16 + l15) * 72 + col];
#pragma unroll
      for (int mt = 0; mt < 4; ++mt) {
        short8 af = *(const short8*)&sA[(mt * 16 + l15) * 72 + col];
#pragma unroll
        for (int nt = 0; nt < 3; ++nt)
          acc[mt][nt] = __builtin_amdgcn_mfma_f32_16x16x32_bf16(
              af, bf[nt], acc[mt][nt], 0, 0, 0);
      }
    }
  }
  __syncthreads();   // sA/sB dead after this; regions below are wave-private

  // ---- epilogue: acc -> wave-private LDS tiles (no barrier needed after) ----
  // per-head region 3392 u16: Q[64][20] @0, K[64][20] @1280, VT[16][52] @2560.
  // Rows 49..63 are finite garbage (projections of clamped row 48) -- masked
  // downstream, so writes are unpredicated. Pitch 20 keeps writes 2-way-free.
  u16* Qh = smem + wv * 3392;
  u16* Kh = Qh + 1280;
  u16* Vh = Kh + 1280;
#pragma unroll
  for (int mt = 0; mt < 4; ++mt) {
#pragma unroll
    for (int r = 0; r < 4; ++r) {
      int tok = mt * 16 + kbase + r;
      Qh[tok * 20 + l15] = f2bf(acc[mt][0][r]);
      Kh[tok * 20 + l15] = f2bf(acc[mt][1][r]);
    }
    // VT[d=l15][tok]: one 8B store; mt=3 only quad 0 fits (cols 48..51,
    // 49..51 finite garbage, never unmasked).
    int tok0 = mt * 16 + kbase;
    if (mt < 3 || quad == 0) {
      short4b pv;
#pragma unroll
      for (int r = 0; r < 4; ++r) pv[r] = (short)f2bf(fmaxf(acc[mt][2][r], 0.0f));
      *(short4b*)&Vh[l15 * 52 + tok0] = pv;
    }
  }

  // ---- attention (wave-private; compiler orders own ds write->read) ----
  const float SM = 0.36067376022224085f;          // dh^-0.5 * log2(e)
  short4b ka[4], vf[4];
#pragma unroll
  for (int t = 0; t < 4; ++t) {
    ka[t] = *(const short4b*)&Kh[(t * 16 + l15) * 20 + kbase];
    // vf[3] quads 1..3 read past the VT row / region: finite stale LDS,
    // multiplied by pf=0 (ktok>=49 masked). quad0 col 48 is the real tail.
    vf[t] = *(const short4b*)&Vh[l15 * 52 + t * 16 + kbase];
  }
  f32x4 zz = (f32x4)(0.0f);
  const size_t obase0 = (size_t)(b * 256 + nb * 64 + wv * 16) * 3136;

#pragma unroll
  for (int qh = 0; qh < 2; ++qh) {               // q-split: bounds VGPR peak
    short4b qb[2];
#pragma unroll
    for (int ntl = 0; ntl < 2; ++ntl)
      qb[ntl] = *(const short4b*)&Qh[((qh * 2 + ntl) * 16 + l15) * 20 + kbase];

    f32x4 s[4][2];                     // S^T tiles: [mt over ktok][ntl over q]
#pragma unroll
    for (int mt = 0; mt < 4; ++mt)
#pragma unroll
      for (int ntl = 0; ntl < 2; ++ntl)
        s[mt][ntl] = __builtin_amdgcn_mfma_f32_16x16x16bf16_1k(
            ka[mt], qb[ntl], zz, 0, 0, 0);

    float inv_sum[2];
    short4b pf[4][2];                  // P^T frags == B-operand layout
#pragma unroll
    for (int ntl = 0; ntl < 2; ++ntl) {
      float m = -1e30f;
#pragma unroll
      for (int mt = 0; mt < 4; ++mt)
#pragma unroll
        for (int r = 0; r < 4; ++r) {
          int kt = mt * 16 + kbase + r;
          float v = (kt < 49) ? s[mt][ntl][r] : -1e30f;
          m = fmaxf(m, v);
        }
      m = fmaxf(m, __shfl_xor(m, 16, 64));
      m = fmaxf(m, __shfl_xor(m, 32, 64));
      float sum = 0.0f;
#pragma unroll
      for (int mt = 0; mt < 4; ++mt)
#pragma unroll
        for (int r = 0; r < 4; ++r) {
          int kt = mt * 16 + kbase + r;
          float p = (kt < 49) ? exp2f((s[mt][ntl][r] - m) * SM) : 0.0f;
          sum += p;
          pf[mt][ntl][r] = (short)f2bf(p);
        }
      sum += __shfl_xor(sum, 16, 64);
      sum += __shfl_xor(sum, 32, 64);
      inv_sum[ntl] = 1.0f / sum;       // defer normalize to store
    }

    f32x4 o[2];
#pragma unroll
    for (int ntl = 0; ntl < 2; ++ntl) o[ntl] = zz;
#pragma unroll
    for (int kt = 0; kt < 4; ++kt)
#pragma unroll
      for (int ntl = 0; ntl < 2; ++ntl)
        o[ntl] = __builtin_amdgcn_mfma_f32_16x16x16bf16_1k(
            vf[kt], pf[kt][ntl], o[ntl], 0, 0, 0);

    // direct store: lane holds O[q=qh*32+ntl*16+l15][d=kbase+r]
#pragma unroll
    for (int ntl = 0; ntl < 2; ++ntl) {
      int q = qh * 32 + ntl * 16 + l15;
      if (q < 49) {
        int tsh = q / 7, tsw = q - tsh * 7;
        size_t pbase = obase0 + (size_t)(tsh * 8 + wh) * 56 + tsw * 8 + ww;
#pragma unroll
        for (int r = 0; r < 4; ++r)
          out[pbase + (size_t)(kbase + r) * 3136] = o[ntl][r] * inv_sum[ntl];
      }
    }
  }
}

extern "C" void kernel_launch(void* const* d_in, const int* in_sizes, int n_in,
                              void* d_out, int out_size, void* d_ws, size_t ws_size,
                              hipStream_t stream) {
  const float* x   = (const float*)d_in[0];
  const float* g   = (const float*)d_in[1];
  const float* be  = (const float*)d_in[2];
  const float* mu  = (const float*)d_in[3];
  const float* va  = (const float*)d_in[4];
  const float* qkw = (const float*)d_in[5];
  const float* vw  = (const float*)d_in[6];
  float* outp = (float*)d_out;

  const size_t AWS_BYTES = (size_t)200704 * 256 * 2;   // 98.0 MB token matrix
  u16* aws = (u16*)d_ws;
  u16* wb  = (u16*)((char*)d_ws + AWS_BYTES);          // 0.39 MB packed weights

  k0_wpack<<<96, 256, 0, stream>>>(qkw, vw, wb);
  k1_bn_gather<<<64 * 8 * 7, 256, 0, stream>>>(x, g, be, mu, va, aws);
  k2_fused<<<64 * 64 * 4, 256, 0, stream>>>(aws, wb, outp);
}